// Round 8
// baseline (284.430 us; speedup 1.0000x reference)
//
#include <hip/hip_runtime.h>

#define NUM_TAG 1024
#define TAG_DIM 128
#define NROWS   131072      // B*W = 128*1024
#define FLAG_M  1.25e-4f    // flag margin: >> 2*delta + np rounding windows
#define RPG     8           // rows per group in exact_fix

typedef __attribute__((ext_vector_type(8))) short short8;
typedef __attribute__((ext_vector_type(4))) float f32x4;

// Exact 2-way bf16 split: x = h + m + (residual < 2^-16 |x|), h/m bf16-exact.
__device__ inline void split2(float xv, unsigned short& h, unsigned short& m) {
    unsigned xb = __float_as_uint(xv);
    unsigned hb = xb & 0xFFFF0000u;
    float r1 = xv - __uint_as_float(hb);        // Sterbenz-exact
    unsigned mb = __float_as_uint(r1) & 0xFFFF0000u;
    h = (unsigned short)(hb >> 16);
    m = (unsigned short)(mb >> 16);
}

// async global->LDS, 16B per lane (linear LDS dest = wave-uniform base + lane*16)
__device__ inline void gld_lds16(const void* g, void* l) {
    __builtin_amdgcn_global_load_lds(
        (const __attribute__((address_space(1))) void*)g,
        (__attribute__((address_space(3))) void*)l, 16, 0, 0);
}

// -------- fused prep: frag-split codebook + scc + zero count --------
// Chunk = 32 codes: 2 arrays (h,m) x 4 s x 2 c x 64 lanes x 8 elems
//       = 8192 ushorts = 16 KB. 32 chunks total.
// cbf[ch*8192 + ((arr*8 + s*2 + c)*64 + l)*8 + e]
//   = split(cb[ch*32 + c*16 + (l&15)][s*32 + (l>>4)*8 + e])
// scc[k] = ||cb_k||^2 in round-1 sequential order (bit-identical).
__global__ __launch_bounds__(256) void prep_kernel(
    const float* __restrict__ cb, float* __restrict__ scc,
    unsigned short* __restrict__ cbf, int* __restrict__ count)
{
    int t = blockIdx.x * 256 + threadIdx.x;
    if (t == 0) count[0] = 0;
    {
        int l  = t & 63;
        int c  = (t >> 6) & 1;
        int s  = (t >> 7) & 3;
        int ch = t >> 9;
        int k  = ch * 32 + c * 16 + (l & 15);
        int d0 = s * 32 + (l >> 4) * 8;
        const float4* xp = reinterpret_cast<const float4*>(cb) + k * 32 + (d0 >> 2);
        float4 v0 = xp[0], v1 = xp[1];
        float xv[8] = {v0.x, v0.y, v0.z, v0.w, v1.x, v1.y, v1.z, v1.w};
        short8 hh, mm;
#pragma unroll
        for (int e = 0; e < 8; ++e) {
            unsigned short h, m;
            split2(xv[e], h, m);
            hh[e] = (short)h; mm[e] = (short)m;
        }
        long baseh = (long)ch * 8192 + (((0 * 8) + s * 2 + c) * 64 + l) * 8;
        long basem = (long)ch * 8192 + (((1 * 8) + s * 2 + c) * 64 + l) * 8;
        *reinterpret_cast<short8*>(cbf + baseh) = hh;
        *reinterpret_cast<short8*>(cbf + basem) = mm;
    }
    if (t < NUM_TAG) {
        const float4* row = reinterpret_cast<const float4*>(cb) + t * (TAG_DIM / 4);
        float s = 0.f;
#pragma unroll
        for (int i = 0; i < TAG_DIM / 4; ++i) {
            float4 v = row[i];
            s += v.x * v.x; s += v.y * v.y; s += v.z * v.z; s += v.w * v.w;
        }
        scc[t] = s;
    }
}

// -------- pass A: split-bf16 MFMA scores + top-2 + near-tie flag append --------
// 256 threads = 4 waves, 128 rows/block, 1024 blocks. B staged via
// global_load_lds TRIPLE buffer, 2 chunks ahead, counted vmcnt(4) at the
// barrier (never 0 in-loop) so one chunk's loads stay in flight (T4).
// scc lives in LDS so fold issues no VMEM (keeps the vmcnt FIFO = staging only).
// Per-code scores bit-identical to rounds 3-7.
__global__ __launch_bounds__(256, 3) void argmin_mfma_kernel(
    const float* __restrict__ x,
    const unsigned short* __restrict__ cbf,
    const float* __restrict__ scc,
    float* __restrict__ fidx_out,
    int* __restrict__ list, int* __restrict__ count)
{
    __shared__ __align__(16) unsigned short lds[3][8192];   // 3 x 16 KB
    __shared__ float scc_lds[NUM_TAG];                      // 4 KB

    const int tid = threadIdx.x;
    const int w   = tid >> 6;
    const int l   = tid & 63;
    const int l15 = l & 15;
    const int l4  = l >> 4;
    const int row0 = blockIdx.x * 128 + w * 32;

    // stage scc -> LDS (published by the first barrier's lgkmcnt(0))
    reinterpret_cast<float4*>(scc_lds)[tid] =
        reinterpret_cast<const float4*>(scc)[tid];

    // ---- A fragments: lane holds row l15 (+16*rf), k-slice l4*8+e, step s ----
    short8 Ah[2][4], Am[2][4];
#pragma unroll
    for (int rf = 0; rf < 2; ++rf) {
        const float4* xp = reinterpret_cast<const float4*>(x) +
                           (long)(row0 + rf * 16 + l15) * 32 + l4 * 2;
#pragma unroll
        for (int s = 0; s < 4; ++s) {
            float4 v0 = xp[s * 8];
            float4 v1 = xp[s * 8 + 1];
            float xv[8] = {v0.x, v0.y, v0.z, v0.w, v1.x, v1.y, v1.z, v1.w};
#pragma unroll
            for (int e = 0; e < 8; ++e) {
                unsigned short h, m;
                split2(xv[e], h, m);
                Ah[rf][s][e] = (short)h;
                Am[rf][s][e] = (short)m;
            }
        }
    }

    float m1[2][4], m2[2][4]; int i1[2][4];
#pragma unroll
    for (int rf = 0; rf < 2; ++rf)
#pragma unroll
        for (int r = 0; r < 4; ++r) { m1[rf][r] = 3.4e38f; m2[rf][r] = 3.4e38f; i1[rf][r] = 0; }

    const float4* gsrc = reinterpret_cast<const float4*>(cbf);  // chunk = 1024 float4

    // ---- prologue: stage chunks 0,1 (8 loads in flight) ----
#pragma unroll
    for (int i = 0; i < 4; ++i)
        gld_lds16(gsrc + i * 256 + tid, (void*)&lds[0][(i * 256 + tid) * 8]);
#pragma unroll
    for (int i = 0; i < 4; ++i)
        gld_lds16(gsrc + 1024 + i * 256 + tid, (void*)&lds[1][(i * 256 + tid) * 8]);

    for (int ch = 0; ch < 32; ++ch) {
        const int b = ch % 3;
        // wait: chunk ch complete (oldest); chunk ch+1's 4 loads may stay in flight
        if (ch == 0)
            asm volatile("s_waitcnt vmcnt(4) lgkmcnt(0)" ::: "memory");
        else if (ch < 31)
            asm volatile("s_waitcnt vmcnt(4)" ::: "memory");
        else
            asm volatile("s_waitcnt vmcnt(0)" ::: "memory");
        __builtin_amdgcn_s_barrier();
        __builtin_amdgcn_sched_barrier(0);

        // issue stage of chunk ch+2 into the buffer freed by compute(ch-1)
        if (ch + 2 < 32) {
            const int nb = (ch + 2) % 3;
            const float4* gp = gsrc + (ch + 2) * 1024 + tid;
#pragma unroll
            for (int i = 0; i < 4; ++i)
                gld_lds16(gp + i * 256, (void*)&lds[nb][(i * 256 + tid) * 8]);
        }

        const int col0 = ch << 5;
        f32x4 acc[2][2];
#pragma unroll
        for (int rf = 0; rf < 2; ++rf)
#pragma unroll
            for (int c = 0; c < 2; ++c) acc[rf][c] = (f32x4)0.f;

#pragma unroll
        for (int s = 0; s < 4; ++s) {
#pragma unroll
            for (int c = 0; c < 2; ++c) {
                const short8 Bh = *reinterpret_cast<const short8*>(
                    &lds[b][(((0 * 8) + s * 2 + c) * 64 + l) * 8]);
                const short8 Bm = *reinterpret_cast<const short8*>(
                    &lds[b][(((1 * 8) + s * 2 + c) * 64 + l) * 8]);
#pragma unroll
                for (int rf = 0; rf < 2; ++rf) {
                    acc[rf][c] = __builtin_amdgcn_mfma_f32_16x16x32_bf16(Ah[rf][s], Bm, acc[rf][c], 0, 0, 0);
                    acc[rf][c] = __builtin_amdgcn_mfma_f32_16x16x32_bf16(Am[rf][s], Bh, acc[rf][c], 0, 0, 0);
                    acc[rf][c] = __builtin_amdgcn_mfma_f32_16x16x32_bf16(Ah[rf][s], Bh, acc[rf][c], 0, 0, 0);
                }
            }
        }

        // fold into running top-2 per output row (k ascending per lane)
#pragma unroll
        for (int c = 0; c < 2; ++c) {
            const int k = col0 + c * 16 + l15;
            const float sccv = scc_lds[k];     // LDS: no VMEM in the loop body
#pragma unroll
            for (int rf = 0; rf < 2; ++rf)
#pragma unroll
                for (int r = 0; r < 4; ++r) {
                    float score = sccv - 2.0f * acc[rf][c][r];
                    if (score < m1[rf][r]) {
                        m2[rf][r] = m1[rf][r]; m1[rf][r] = score; i1[rf][r] = k;
                    } else if (score < m2[rf][r]) {
                        m2[rf][r] = score;
                    }
                }
        }
    }

    // ---- cross-lane top-2 merge within each 16-lane col group ----
#pragma unroll
    for (int rf = 0; rf < 2; ++rf)
#pragma unroll
        for (int r = 0; r < 4; ++r) {
            float v1 = m1[rf][r], v2 = m2[rf][r]; int ii = i1[rf][r];
#pragma unroll
            for (int mk = 1; mk < 16; mk <<= 1) {
                float o1 = __shfl_xor(v1, mk, 64);
                float o2 = __shfl_xor(v2, mk, 64);
                int   oi = __shfl_xor(ii, mk, 64);
                float n2 = fminf(fminf(v2, o2), fmaxf(v1, o1));  // global 2nd-min
                if (o1 < v1 || (o1 == v1 && oi < ii)) { v1 = o1; ii = oi; }
                v2 = n2;
            }
            if (l15 == 0) {
                int row = row0 + rf * 16 + l4 * 4 + r;
                fidx_out[row] = (float)ii;
                if (v2 - v1 <= FLAG_M) {           // near-tie: append for exact rescore
                    int pos = atomicAdd(count, 1); // list order nondet; results per-row
                    list[pos] = row;               // independent -> output deterministic
                }
            }
        }
}

// -------- pass B: exact rescore, RPG rows per block-group --------
// Per (row,code): sequential fp32 fmac dot (i ascending, x/y/z/w), dist =
// (sxx+scc) - 2*dot, tie -> lowest k. Bit-identical to the round-1 recipe.
__global__ __launch_bounds__(256) void exact_fix_kernel(
    const float* __restrict__ x, const float* __restrict__ cb,
    const float* __restrict__ scc, const int* __restrict__ list,
    const int* __restrict__ count, float* __restrict__ fidx_out)
{
    __shared__ float4 Xs[RPG][32];
    __shared__ float  sxxs[RPG];
    __shared__ float  wrv[RPG][4];
    __shared__ int    wri[RPG][4];
    __shared__ int    rows_s[RPG];

    const int tid  = threadIdx.x;
    const int lane = tid & 63;
    const int wv   = tid >> 6;
    const int nflag = count[0];
    const int ngroups = (nflag + RPG - 1) / RPG;

    for (int g = blockIdx.x; g < ngroups; g += gridDim.x) {
        const int nr = min(RPG, nflag - g * RPG);
        if (tid < RPG)
            rows_s[tid] = list[g * RPG + min(tid, nr - 1)];   // dup last for tail
        __syncthreads();
        {   // stage 8 rows x 32 float4
            int r = tid >> 5, i = tid & 31;
            Xs[r][i] = reinterpret_cast<const float4*>(x)[(long)rows_s[r] * 32 + i];
        }
        __syncthreads();
        if (tid < RPG) {   // per-row sxx, sequential order
            float s = 0.f;
            for (int i = 0; i < 32; ++i) {
                float4 v = Xs[tid][i];
                s += v.x * v.x; s += v.y * v.y; s += v.z * v.z; s += v.w * v.w;
            }
            sxxs[tid] = s;
        }
        __syncthreads();

        // 4 codes per thread: k = tid*4+j (in-thread ascending)
        float acc[RPG][4];
#pragma unroll
        for (int r = 0; r < RPG; ++r)
#pragma unroll
            for (int j = 0; j < 4; ++j) acc[r][j] = 0.f;

        const float4* crow = reinterpret_cast<const float4*>(cb) + (tid * 4) * 32;
        for (int i = 0; i < 32; ++i) {
            float4 xv[RPG];
#pragma unroll
            for (int r = 0; r < RPG; ++r) xv[r] = Xs[r][i];
#pragma unroll
            for (int j = 0; j < 4; ++j) {
                float4 c = crow[j * 32 + i];
#pragma unroll
                for (int r = 0; r < RPG; ++r) {
                    acc[r][j] += xv[r].x * c.x;
                    acc[r][j] += xv[r].y * c.y;
                    acc[r][j] += xv[r].z * c.z;
                    acc[r][j] += xv[r].w * c.w;
                }
            }
        }

#pragma unroll
        for (int r = 0; r < RPG; ++r) {
            float bv = 3.4e38f; int bi = 0;
            const float sxxv = sxxs[r];
#pragma unroll
            for (int j = 0; j < 4; ++j) {
                int k = tid * 4 + j;
                float s1 = sxxv + scc[k];          // np: (sxx + scc)
                float dist = s1 - 2.0f * acc[r][j]; // np: ... - 2*dot
                if (dist < bv) { bv = dist; bi = k; }
            }
            // wave reduce (tie -> lowest k)
#pragma unroll
            for (int mk = 1; mk < 64; mk <<= 1) {
                float ov = __shfl_xor(bv, mk, 64);
                int   oi = __shfl_xor(bi, mk, 64);
                if (ov < bv || (ov == bv && oi < bi)) { bv = ov; bi = oi; }
            }
            if (lane == 0) { wrv[r][wv] = bv; wri[r][wv] = bi; }
        }
        __syncthreads();
        if (tid < RPG && tid < nr) {
            float bv = wrv[tid][0]; int bi = wri[tid][0];
#pragma unroll
            for (int e = 1; e < 4; ++e) {
                float v = wrv[tid][e]; int oi = wri[tid][e];
                if (v < bv || (v == bv && oi < bi)) { bv = v; bi = oi; }
            }
            fidx_out[rows_s[tid]] = (float)bi;
        }
        __syncthreads();
    }
}

// -------- phase 2: gather + STE output + loss partials --------
__global__ __launch_bounds__(256) void quant_kernel(
    const float* __restrict__ x, const float* __restrict__ cb,
    const float* __restrict__ fidx, float* __restrict__ out,
    double* __restrict__ partial)
{
    const int N4 = NROWS * (TAG_DIM / 4);
    double s = 0.0;
    for (int i = blockIdx.x * blockDim.x + threadIdx.x; i < N4; i += gridDim.x * blockDim.x) {
        int n = i >> 5;
        int d4 = i & 31;
        int k = (int)fidx[n];
        float4 xv = reinterpret_cast<const float4*>(x)[i];
        float4 qv = reinterpret_cast<const float4*>(cb)[k * 32 + d4];
        float dx = qv.x - xv.x, dy = qv.y - xv.y, dz = qv.z - xv.z, dw = qv.w - xv.w;
        float4 o;
        o.x = xv.x + dx; o.y = xv.y + dy; o.z = xv.z + dz; o.w = xv.w + dw;
        reinterpret_cast<float4*>(out)[i] = o;
        s += (double)dx * dx; s += (double)dy * dy; s += (double)dz * dz; s += (double)dw * dw;
    }
    __shared__ double sd[256];
    sd[threadIdx.x] = s;
    __syncthreads();
    for (int off = 128; off > 0; off >>= 1) {
        if (threadIdx.x < (unsigned)off) sd[threadIdx.x] += sd[threadIdx.x + off];
        __syncthreads();
    }
    if (threadIdx.x == 0) partial[blockIdx.x] = sd[0];
}

__global__ __launch_bounds__(256) void loss_kernel(
    const double* __restrict__ partial, int n, float* __restrict__ out_loss)
{
    __shared__ double sd[256];
    double s = 0.0;
    for (int i = threadIdx.x; i < n; i += 256) s += partial[i];
    sd[threadIdx.x] = s;
    __syncthreads();
    for (int off = 128; off > 0; off >>= 1) {
        if (threadIdx.x < (unsigned)off) sd[threadIdx.x] += sd[threadIdx.x + off];
        __syncthreads();
    }
    if (threadIdx.x == 0) {
        double mean = sd[0] / (double)((long long)NROWS * TAG_DIM);
        out_loss[0] = (float)(mean + 0.25 * mean);
    }
}

extern "C" void kernel_launch(void* const* d_in, const int* in_sizes, int n_in,
                              void* d_out, int out_size, void* d_ws, size_t ws_size,
                              hipStream_t stream) {
    const float* x  = (const float*)d_in[0];   // [131072][128]
    const float* cb = (const float*)d_in[1];   // [1024][128]
    float* out      = (float*)d_out;
    float* out_loss = out + (long)NROWS * TAG_DIM;
    float* out_fidx = out_loss + 1;            // 131072 indices as f32

    // ws layout (~1.05 MB): scc | cbf | list | count | partial
    char* wsb = (char*)d_ws;
    float*          scc     = (float*)(wsb);                     // 4 KB
    unsigned short* cbf     = (unsigned short*)(wsb + 4096);     // 512 KB
    int*            list    = (int*)(wsb + 528384);              // 512 KB
    int*            count   = (int*)(wsb + 1052672);             // 64 B
    double*         partial = (double*)(wsb + 1052736);          // 16 KB

    prep_kernel      <<<64, 256, 0, stream>>>(cb, scc, cbf, count);
    argmin_mfma_kernel<<<NROWS / 128, 256, 0, stream>>>(x, cbf, scc, out_fidx, list, count);
    exact_fix_kernel <<<512, 256, 0, stream>>>(x, cb, scc, list, count, out_fidx);
    quant_kernel     <<<2048, 256, 0, stream>>>(x, cb, out_fidx, out, partial);
    loss_kernel      <<<1, 256, 0, stream>>>(partial, 2048, out_loss);
}

// Round 9
// 270.349 us; speedup vs baseline: 1.0521x; 1.0521x over previous
//
#include <hip/hip_runtime.h>

#define NUM_TAG 1024
#define TAG_DIM 128
#define NROWS   131072      // B*W = 128*1024
#define FLAG_M  1.25e-4f    // flag margin: >> 2*delta + np rounding windows
#define RPG     8           // rows per group in exact_fix

typedef __attribute__((ext_vector_type(8))) short short8;
typedef __attribute__((ext_vector_type(4))) float f32x4;

// Exact 2-way bf16 split: x = h + m + (residual < 2^-16 |x|), h/m bf16-exact.
__device__ inline void split2(float xv, unsigned short& h, unsigned short& m) {
    unsigned xb = __float_as_uint(xv);
    unsigned hb = xb & 0xFFFF0000u;
    float r1 = xv - __uint_as_float(hb);        // Sterbenz-exact
    unsigned mb = __float_as_uint(r1) & 0xFFFF0000u;
    h = (unsigned short)(hb >> 16);
    m = (unsigned short)(mb >> 16);
}

// async global->LDS, 16B per lane (linear LDS dest = wave-uniform base + lane*16)
__device__ inline void gld_lds16(const void* g, void* l) {
    __builtin_amdgcn_global_load_lds(
        (const __attribute__((address_space(1))) void*)g,
        (__attribute__((address_space(3))) void*)l, 16, 0, 0);
}

// -------- fused prep: frag-split codebook + scc + zero count (r8, verified) ----
// Chunk = 32 codes: 2 arrays (h,m) x 4 s x 2 c x 64 lanes x 8 elems
//       = 8192 ushorts = 16 KB. 32 chunks total.
// cbf[ch*8192 + ((arr*8 + s*2 + c)*64 + l)*8 + e]
//   = split(cb[ch*32 + c*16 + (l&15)][s*32 + (l>>4)*8 + e])
__global__ __launch_bounds__(256) void prep_kernel(
    const float* __restrict__ cb, float* __restrict__ scc,
    unsigned short* __restrict__ cbf, int* __restrict__ count)
{
    int t = blockIdx.x * 256 + threadIdx.x;
    if (t == 0) count[0] = 0;
    {
        int l  = t & 63;
        int c  = (t >> 6) & 1;
        int s  = (t >> 7) & 3;
        int ch = t >> 9;
        int k  = ch * 32 + c * 16 + (l & 15);
        int d0 = s * 32 + (l >> 4) * 8;
        const float4* xp = reinterpret_cast<const float4*>(cb) + k * 32 + (d0 >> 2);
        float4 v0 = xp[0], v1 = xp[1];
        float xv[8] = {v0.x, v0.y, v0.z, v0.w, v1.x, v1.y, v1.z, v1.w};
        short8 hh, mm;
#pragma unroll
        for (int e = 0; e < 8; ++e) {
            unsigned short h, m;
            split2(xv[e], h, m);
            hh[e] = (short)h; mm[e] = (short)m;
        }
        long baseh = (long)ch * 8192 + (((0 * 8) + s * 2 + c) * 64 + l) * 8;
        long basem = (long)ch * 8192 + (((1 * 8) + s * 2 + c) * 64 + l) * 8;
        *reinterpret_cast<short8*>(cbf + baseh) = hh;
        *reinterpret_cast<short8*>(cbf + basem) = mm;
    }
    if (t < NUM_TAG) {
        const float4* row = reinterpret_cast<const float4*>(cb) + t * (TAG_DIM / 4);
        float s = 0.f;
#pragma unroll
        for (int i = 0; i < TAG_DIM / 4; ++i) {
            float4 v = row[i];
            s += v.x * v.x; s += v.y * v.y; s += v.z * v.z; s += v.w * v.w;
        }
        scc[t] = s;
    }
}

// -------- pass A: split-bf16 MFMA scores + top-2 + near-tie flag append --------
// r7's verified loop structure (gld_lds DOUBLE buffer, loads issued at loop
// top, single __syncthreads at loop end) + med3 fold + setprio + scc in LDS.
// Update semantics identical to rounds 3-8: m1/m2 global top-2, i1 on strict <
// with k ascending per lane (tie -> lowest k).
__global__ __launch_bounds__(256, 3) void argmin_mfma_kernel(
    const float* __restrict__ x,
    const unsigned short* __restrict__ cbf,
    const float* __restrict__ scc,
    float* __restrict__ fidx_out,
    int* __restrict__ list, int* __restrict__ count)
{
    __shared__ __align__(16) unsigned short lds[2][8192];   // 2 x 16 KB
    __shared__ float scc_lds[NUM_TAG];                      // 4 KB

    const int tid = threadIdx.x;
    const int w   = tid >> 6;
    const int l   = tid & 63;
    const int l15 = l & 15;
    const int l4  = l >> 4;
    const int row0 = blockIdx.x * 128 + w * 32;

    // stage scc -> LDS (ds_writes published by the prologue __syncthreads)
    reinterpret_cast<float4*>(scc_lds)[tid] =
        reinterpret_cast<const float4*>(scc)[tid];

    // ---- A fragments: lane holds row l15 (+16*rf), k-slice l4*8+e, step s ----
    short8 Ah[2][4], Am[2][4];
#pragma unroll
    for (int rf = 0; rf < 2; ++rf) {
        const float4* xp = reinterpret_cast<const float4*>(x) +
                           (long)(row0 + rf * 16 + l15) * 32 + l4 * 2;
#pragma unroll
        for (int s = 0; s < 4; ++s) {
            float4 v0 = xp[s * 8];
            float4 v1 = xp[s * 8 + 1];
            float xv[8] = {v0.x, v0.y, v0.z, v0.w, v1.x, v1.y, v1.z, v1.w};
#pragma unroll
            for (int e = 0; e < 8; ++e) {
                unsigned short h, m;
                split2(xv[e], h, m);
                Ah[rf][s][e] = (short)h;
                Am[rf][s][e] = (short)m;
            }
        }
    }

    float m1[2][4], m2[2][4]; int i1[2][4];
#pragma unroll
    for (int rf = 0; rf < 2; ++rf)
#pragma unroll
        for (int r = 0; r < 4; ++r) { m1[rf][r] = 3.4e38f; m2[rf][r] = 3.4e38f; i1[rf][r] = 0; }

    const float4* gsrc = reinterpret_cast<const float4*>(cbf);  // chunk = 1024 float4

    // ---- prologue: stage chunk 0 into lds[0] ----
#pragma unroll
    for (int i = 0; i < 4; ++i)
        gld_lds16(gsrc + i * 256 + tid, (void*)&lds[0][(i * 256 + tid) * 8]);
    __syncthreads();   // drains vmcnt(0) + publishes scc_lds

    for (int ch = 0; ch < 32; ++ch) {
        const int b = ch & 1;
        // issue next-chunk loads into the other buffer (fly during compute)
        if (ch < 31) {
            const float4* gp = gsrc + (ch + 1) * 1024 + tid;
#pragma unroll
            for (int i = 0; i < 4; ++i)
                gld_lds16(gp + i * 256, (void*)&lds[b ^ 1][(i * 256 + tid) * 8]);
        }

        const int col0 = ch << 5;
        f32x4 acc[2][2];
#pragma unroll
        for (int rf = 0; rf < 2; ++rf)
#pragma unroll
            for (int c = 0; c < 2; ++c) acc[rf][c] = (f32x4)0.f;

        __builtin_amdgcn_s_setprio(1);
#pragma unroll
        for (int s = 0; s < 4; ++s) {
#pragma unroll
            for (int c = 0; c < 2; ++c) {
                const short8 Bh = *reinterpret_cast<const short8*>(
                    &lds[b][(((0 * 8) + s * 2 + c) * 64 + l) * 8]);
                const short8 Bm = *reinterpret_cast<const short8*>(
                    &lds[b][(((1 * 8) + s * 2 + c) * 64 + l) * 8]);
#pragma unroll
                for (int rf = 0; rf < 2; ++rf) {
                    acc[rf][c] = __builtin_amdgcn_mfma_f32_16x16x32_bf16(Ah[rf][s], Bm, acc[rf][c], 0, 0, 0);
                    acc[rf][c] = __builtin_amdgcn_mfma_f32_16x16x32_bf16(Am[rf][s], Bh, acc[rf][c], 0, 0, 0);
                    acc[rf][c] = __builtin_amdgcn_mfma_f32_16x16x32_bf16(Ah[rf][s], Bh, acc[rf][c], 0, 0, 0);
                }
            }
        }
        __builtin_amdgcn_s_setprio(0);

        // fold into running top-2 per output row (med3 form, same semantics:
        // m2' = med3(s,m1,m2); i1 on strict < vs old m1; m1' = min)
#pragma unroll
        for (int c = 0; c < 2; ++c) {
            const int k = col0 + c * 16 + l15;
            const float sccv = scc_lds[k];     // LDS broadcast, no VMEM in loop
#pragma unroll
            for (int rf = 0; rf < 2; ++rf)
#pragma unroll
                for (int r = 0; r < 4; ++r) {
                    float score = sccv - 2.0f * acc[rf][c][r];
                    m2[rf][r] = __builtin_amdgcn_fmed3f(score, m1[rf][r], m2[rf][r]);
                    i1[rf][r] = (score < m1[rf][r]) ? k : i1[rf][r];
                    m1[rf][r] = fminf(m1[rf][r], score);
                }
        }

        __syncthreads();   // next chunk staged (vmcnt0) + all readers of b done
    }

    // ---- cross-lane top-2 merge within each 16-lane col group ----
#pragma unroll
    for (int rf = 0; rf < 2; ++rf)
#pragma unroll
        for (int r = 0; r < 4; ++r) {
            float v1 = m1[rf][r], v2 = m2[rf][r]; int ii = i1[rf][r];
#pragma unroll
            for (int mk = 1; mk < 16; mk <<= 1) {
                float o1 = __shfl_xor(v1, mk, 64);
                float o2 = __shfl_xor(v2, mk, 64);
                int   oi = __shfl_xor(ii, mk, 64);
                float n2 = fminf(fminf(v2, o2), fmaxf(v1, o1));  // global 2nd-min
                if (o1 < v1 || (o1 == v1 && oi < ii)) { v1 = o1; ii = oi; }
                v2 = n2;
            }
            if (l15 == 0) {
                int row = row0 + rf * 16 + l4 * 4 + r;
                fidx_out[row] = (float)ii;
                if (v2 - v1 <= FLAG_M) {           // near-tie: append for exact rescore
                    int pos = atomicAdd(count, 1); // list order nondet; per-row results
                    list[pos] = row;               // independent -> output deterministic
                }
            }
        }
}

// -------- pass B: exact rescore, RPG rows per block-group --------
// Per (row,code): sequential fp32 fmac dot (i ascending, x/y/z/w), dist =
// (sxx+scc) - 2*dot, tie -> lowest k. Bit-identical to the round-1 recipe.
__global__ __launch_bounds__(256) void exact_fix_kernel(
    const float* __restrict__ x, const float* __restrict__ cb,
    const float* __restrict__ scc, const int* __restrict__ list,
    const int* __restrict__ count, float* __restrict__ fidx_out)
{
    __shared__ float4 Xs[RPG][32];
    __shared__ float  sxxs[RPG];
    __shared__ float  wrv[RPG][4];
    __shared__ int    wri[RPG][4];
    __shared__ int    rows_s[RPG];

    const int tid  = threadIdx.x;
    const int lane = tid & 63;
    const int wv   = tid >> 6;
    const int nflag = count[0];
    const int ngroups = (nflag + RPG - 1) / RPG;

    for (int g = blockIdx.x; g < ngroups; g += gridDim.x) {
        const int nr = min(RPG, nflag - g * RPG);
        if (tid < RPG)
            rows_s[tid] = list[g * RPG + min(tid, nr - 1)];   // dup last for tail
        __syncthreads();
        {   // stage 8 rows x 32 float4
            int r = tid >> 5, i = tid & 31;
            Xs[r][i] = reinterpret_cast<const float4*>(x)[(long)rows_s[r] * 32 + i];
        }
        __syncthreads();
        if (tid < RPG) {   // per-row sxx, sequential order
            float s = 0.f;
            for (int i = 0; i < 32; ++i) {
                float4 v = Xs[tid][i];
                s += v.x * v.x; s += v.y * v.y; s += v.z * v.z; s += v.w * v.w;
            }
            sxxs[tid] = s;
        }
        __syncthreads();

        // 4 codes per thread: k = tid*4+j (in-thread ascending)
        float acc[RPG][4];
#pragma unroll
        for (int r = 0; r < RPG; ++r)
#pragma unroll
            for (int j = 0; j < 4; ++j) acc[r][j] = 0.f;

        const float4* crow = reinterpret_cast<const float4*>(cb) + (tid * 4) * 32;
        for (int i = 0; i < 32; ++i) {
            float4 xv[RPG];
#pragma unroll
            for (int r = 0; r < RPG; ++r) xv[r] = Xs[r][i];
#pragma unroll
            for (int j = 0; j < 4; ++j) {
                float4 c = crow[j * 32 + i];
#pragma unroll
                for (int r = 0; r < RPG; ++r) {
                    acc[r][j] += xv[r].x * c.x;
                    acc[r][j] += xv[r].y * c.y;
                    acc[r][j] += xv[r].z * c.z;
                    acc[r][j] += xv[r].w * c.w;
                }
            }
        }

#pragma unroll
        for (int r = 0; r < RPG; ++r) {
            float bv = 3.4e38f; int bi = 0;
            const float sxxv = sxxs[r];
#pragma unroll
            for (int j = 0; j < 4; ++j) {
                int k = tid * 4 + j;
                float s1 = sxxv + scc[k];          // np: (sxx + scc)
                float dist = s1 - 2.0f * acc[r][j]; // np: ... - 2*dot
                if (dist < bv) { bv = dist; bi = k; }
            }
            // wave reduce (tie -> lowest k)
#pragma unroll
            for (int mk = 1; mk < 64; mk <<= 1) {
                float ov = __shfl_xor(bv, mk, 64);
                int   oi = __shfl_xor(bi, mk, 64);
                if (ov < bv || (ov == bv && oi < bi)) { bv = ov; bi = oi; }
            }
            if (lane == 0) { wrv[r][wv] = bv; wri[r][wv] = bi; }
        }
        __syncthreads();
        if (tid < RPG && tid < nr) {
            float bv = wrv[tid][0]; int bi = wri[tid][0];
#pragma unroll
            for (int e = 1; e < 4; ++e) {
                float v = wrv[tid][e]; int oi = wri[tid][e];
                if (v < bv || (v == bv && oi < bi)) { bv = v; bi = oi; }
            }
            fidx_out[rows_s[tid]] = (float)bi;
        }
        __syncthreads();
    }
}

// -------- phase 2: gather + STE output + loss partials --------
__global__ __launch_bounds__(256) void quant_kernel(
    const float* __restrict__ x, const float* __restrict__ cb,
    const float* __restrict__ fidx, float* __restrict__ out,
    double* __restrict__ partial)
{
    const int N4 = NROWS * (TAG_DIM / 4);
    double s = 0.0;
    for (int i = blockIdx.x * blockDim.x + threadIdx.x; i < N4; i += gridDim.x * blockDim.x) {
        int n = i >> 5;
        int d4 = i & 31;
        int k = (int)fidx[n];
        float4 xv = reinterpret_cast<const float4*>(x)[i];
        float4 qv = reinterpret_cast<const float4*>(cb)[k * 32 + d4];
        float dx = qv.x - xv.x, dy = qv.y - xv.y, dz = qv.z - xv.z, dw = qv.w - xv.w;
        float4 o;
        o.x = xv.x + dx; o.y = xv.y + dy; o.z = xv.z + dz; o.w = xv.w + dw;
        reinterpret_cast<float4*>(out)[i] = o;
        s += (double)dx * dx; s += (double)dy * dy; s += (double)dz * dz; s += (double)dw * dw;
    }
    __shared__ double sd[256];
    sd[threadIdx.x] = s;
    __syncthreads();
    for (int off = 128; off > 0; off >>= 1) {
        if (threadIdx.x < (unsigned)off) sd[threadIdx.x] += sd[threadIdx.x + off];
        __syncthreads();
    }
    if (threadIdx.x == 0) partial[blockIdx.x] = sd[0];
}

__global__ __launch_bounds__(256) void loss_kernel(
    const double* __restrict__ partial, int n, float* __restrict__ out_loss)
{
    __shared__ double sd[256];
    double s = 0.0;
    for (int i = threadIdx.x; i < n; i += 256) s += partial[i];
    sd[threadIdx.x] = s;
    __syncthreads();
    for (int off = 128; off > 0; off >>= 1) {
        if (threadIdx.x < (unsigned)off) sd[threadIdx.x] += sd[threadIdx.x + off];
        __syncthreads();
    }
    if (threadIdx.x == 0) {
        double mean = sd[0] / (double)((long long)NROWS * TAG_DIM);
        out_loss[0] = (float)(mean + 0.25 * mean);
    }
}

extern "C" void kernel_launch(void* const* d_in, const int* in_sizes, int n_in,
                              void* d_out, int out_size, void* d_ws, size_t ws_size,
                              hipStream_t stream) {
    const float* x  = (const float*)d_in[0];   // [131072][128]
    const float* cb = (const float*)d_in[1];   // [1024][128]
    float* out      = (float*)d_out;
    float* out_loss = out + (long)NROWS * TAG_DIM;
    float* out_fidx = out_loss + 1;            // 131072 indices as f32

    // ws layout (~1.05 MB): scc | cbf | list | count | partial
    char* wsb = (char*)d_ws;
    float*          scc     = (float*)(wsb);                     // 4 KB
    unsigned short* cbf     = (unsigned short*)(wsb + 4096);     // 512 KB
    int*            list    = (int*)(wsb + 528384);              // 512 KB
    int*            count   = (int*)(wsb + 1052672);             // 64 B
    double*         partial = (double*)(wsb + 1052736);          // 16 KB

    prep_kernel       <<<64, 256, 0, stream>>>(cb, scc, cbf, count);
    argmin_mfma_kernel<<<NROWS / 128, 256, 0, stream>>>(x, cbf, scc, out_fidx, list, count);
    exact_fix_kernel  <<<512, 256, 0, stream>>>(x, cb, scc, list, count, out_fidx);
    quant_kernel      <<<2048, 256, 0, stream>>>(x, cb, out_fidx, out, partial);
    loss_kernel       <<<1, 256, 0, stream>>>(partial, 2048, out_loss);
}

// Round 10
// 245.688 us; speedup vs baseline: 1.1577x; 1.1004x over previous
//
#include <hip/hip_runtime.h>

#define NUM_TAG 1024
#define TAG_DIM 128
#define NROWS   131072      // B*W = 128*1024
#define FLAG_M  1.25e-4f    // flag margin: >> 2*delta + np rounding windows
#define RPG     8           // rows per group in exact_fix
#define RF      4           // 16-row A fragments per wave (64 rows/wave)

typedef __attribute__((ext_vector_type(8))) short short8;
typedef __attribute__((ext_vector_type(4))) float f32x4;

// Exact 2-way bf16 split: x = h + m + (residual < 2^-16 |x|), h/m bf16-exact.
__device__ inline void split2(float xv, unsigned short& h, unsigned short& m) {
    unsigned xb = __float_as_uint(xv);
    unsigned hb = xb & 0xFFFF0000u;
    float r1 = xv - __uint_as_float(hb);        // Sterbenz-exact
    unsigned mb = __float_as_uint(r1) & 0xFFFF0000u;
    h = (unsigned short)(hb >> 16);
    m = (unsigned short)(mb >> 16);
}

// async global->LDS, 16B per lane (linear LDS dest = wave-uniform base + lane*16)
__device__ inline void gld_lds16(const void* g, void* l) {
    __builtin_amdgcn_global_load_lds(
        (const __attribute__((address_space(1))) void*)g,
        (__attribute__((address_space(3))) void*)l, 16, 0, 0);
}

// -------- fused prep: frag-split codebook + scc + zero count (verified r8/r9) --
// Chunk = 32 codes: 2 arrays (h,m) x 4 s x 2 c x 64 lanes x 8 elems
//       = 8192 ushorts = 16 KB. 32 chunks total.
// cbf[ch*8192 + ((arr*8 + s*2 + c)*64 + l)*8 + e]
//   = split(cb[ch*32 + c*16 + (l&15)][s*32 + (l>>4)*8 + e])
__global__ __launch_bounds__(256) void prep_kernel(
    const float* __restrict__ cb, float* __restrict__ scc,
    unsigned short* __restrict__ cbf, int* __restrict__ count)
{
    int t = blockIdx.x * 256 + threadIdx.x;
    if (t == 0) count[0] = 0;
    {
        int l  = t & 63;
        int c  = (t >> 6) & 1;
        int s  = (t >> 7) & 3;
        int ch = t >> 9;
        int k  = ch * 32 + c * 16 + (l & 15);
        int d0 = s * 32 + (l >> 4) * 8;
        const float4* xp = reinterpret_cast<const float4*>(cb) + k * 32 + (d0 >> 2);
        float4 v0 = xp[0], v1 = xp[1];
        float xv[8] = {v0.x, v0.y, v0.z, v0.w, v1.x, v1.y, v1.z, v1.w};
        short8 hh, mm;
#pragma unroll
        for (int e = 0; e < 8; ++e) {
            unsigned short h, m;
            split2(xv[e], h, m);
            hh[e] = (short)h; mm[e] = (short)m;
        }
        long baseh = (long)ch * 8192 + (((0 * 8) + s * 2 + c) * 64 + l) * 8;
        long basem = (long)ch * 8192 + (((1 * 8) + s * 2 + c) * 64 + l) * 8;
        *reinterpret_cast<short8*>(cbf + baseh) = hh;
        *reinterpret_cast<short8*>(cbf + basem) = mm;
    }
    if (t < NUM_TAG) {
        const float4* row = reinterpret_cast<const float4*>(cb) + t * (TAG_DIM / 4);
        float s = 0.f;
#pragma unroll
        for (int i = 0; i < TAG_DIM / 4; ++i) {
            float4 v = row[i];
            s += v.x * v.x; s += v.y * v.y; s += v.z * v.z; s += v.w * v.w;
        }
        scc[t] = s;
    }
}

// -------- pass A: split-bf16 MFMA scores + top-2 + near-tie flag append --------
// 256 threads = 4 waves, 64 rows/wave (RF=4), 256 rows/block, 512 blocks
// (whole grid resident: 2 blocks/CU). r7's verified loop skeleton: gld_lds
// double buffer, next-chunk loads issued at loop top, one __syncthreads per
// chunk. 16 ds_read_b128 feed 96 MFMAs per wave-chunk (B shared across RF).
// Per-output-row score sequence bit-identical to rounds 3-9.
__global__ __launch_bounds__(256, 2) void argmin_mfma_kernel(
    const float* __restrict__ x,
    const unsigned short* __restrict__ cbf,
    const float* __restrict__ scc,
    float* __restrict__ fidx_out,
    int* __restrict__ list, int* __restrict__ count)
{
    __shared__ __align__(16) unsigned short lds[2][8192];   // 2 x 16 KB
    __shared__ float scc_lds[NUM_TAG];                      // 4 KB

    const int tid = threadIdx.x;
    const int w   = tid >> 6;
    const int l   = tid & 63;
    const int l15 = l & 15;
    const int l4  = l >> 4;
    const int row0 = blockIdx.x * 256 + w * 64;

    // stage scc -> LDS (published by the prologue __syncthreads)
    reinterpret_cast<float4*>(scc_lds)[tid] =
        reinterpret_cast<const float4*>(scc)[tid];

    // ---- A fragments: lane holds row l15 (+16*rf), k-slice l4*8+e, step s ----
    short8 Ah[RF][4], Am[RF][4];
#pragma unroll
    for (int rf = 0; rf < RF; ++rf) {
        const float4* xp = reinterpret_cast<const float4*>(x) +
                           (long)(row0 + rf * 16 + l15) * 32 + l4 * 2;
#pragma unroll
        for (int s = 0; s < 4; ++s) {
            float4 v0 = xp[s * 8];
            float4 v1 = xp[s * 8 + 1];
            float xv[8] = {v0.x, v0.y, v0.z, v0.w, v1.x, v1.y, v1.z, v1.w};
#pragma unroll
            for (int e = 0; e < 8; ++e) {
                unsigned short h, m;
                split2(xv[e], h, m);
                Ah[rf][s][e] = (short)h;
                Am[rf][s][e] = (short)m;
            }
        }
    }

    float m1[RF][4], m2[RF][4]; int i1[RF][4];
#pragma unroll
    for (int rf = 0; rf < RF; ++rf)
#pragma unroll
        for (int r = 0; r < 4; ++r) { m1[rf][r] = 3.4e38f; m2[rf][r] = 3.4e38f; i1[rf][r] = 0; }

    const float4* gsrc = reinterpret_cast<const float4*>(cbf);  // chunk = 1024 float4

    // ---- prologue: stage chunk 0 into lds[0] ----
#pragma unroll
    for (int i = 0; i < 4; ++i)
        gld_lds16(gsrc + i * 256 + tid, (void*)&lds[0][(i * 256 + tid) * 8]);
    __syncthreads();   // drains vmcnt(0) + publishes scc_lds

    for (int ch = 0; ch < 32; ++ch) {
        const int b = ch & 1;
        // issue next-chunk loads into the other buffer (fly during compute)
        if (ch < 31) {
            const float4* gp = gsrc + (ch + 1) * 1024 + tid;
#pragma unroll
            for (int i = 0; i < 4; ++i)
                gld_lds16(gp + i * 256, (void*)&lds[b ^ 1][(i * 256 + tid) * 8]);
        }

        const int col0 = ch << 5;
        f32x4 acc[RF][2];
#pragma unroll
        for (int rf = 0; rf < RF; ++rf)
#pragma unroll
            for (int c = 0; c < 2; ++c) acc[rf][c] = (f32x4)0.f;

#pragma unroll
        for (int s = 0; s < 4; ++s) {
#pragma unroll
            for (int c = 0; c < 2; ++c) {
                const short8 Bh = *reinterpret_cast<const short8*>(
                    &lds[b][(((0 * 8) + s * 2 + c) * 64 + l) * 8]);
                const short8 Bm = *reinterpret_cast<const short8*>(
                    &lds[b][(((1 * 8) + s * 2 + c) * 64 + l) * 8]);
#pragma unroll
                for (int rf = 0; rf < RF; ++rf) {
                    acc[rf][c] = __builtin_amdgcn_mfma_f32_16x16x32_bf16(Ah[rf][s], Bm, acc[rf][c], 0, 0, 0);
                    acc[rf][c] = __builtin_amdgcn_mfma_f32_16x16x32_bf16(Am[rf][s], Bh, acc[rf][c], 0, 0, 0);
                    acc[rf][c] = __builtin_amdgcn_mfma_f32_16x16x32_bf16(Ah[rf][s], Bh, acc[rf][c], 0, 0, 0);
                }
            }
        }

        // fold into running top-2 per output row (med3 form, verified r9:
        // m2' = med3(s,m1,m2); i1 on strict < vs old m1; m1' = min)
#pragma unroll
        for (int c = 0; c < 2; ++c) {
            const int k = col0 + c * 16 + l15;
            const float sccv = scc_lds[k];     // LDS broadcast, no VMEM in loop
#pragma unroll
            for (int rf = 0; rf < RF; ++rf)
#pragma unroll
                for (int r = 0; r < 4; ++r) {
                    float score = sccv - 2.0f * acc[rf][c][r];
                    m2[rf][r] = __builtin_amdgcn_fmed3f(score, m1[rf][r], m2[rf][r]);
                    i1[rf][r] = (score < m1[rf][r]) ? k : i1[rf][r];
                    m1[rf][r] = fminf(m1[rf][r], score);
                }
        }

        __syncthreads();   // next chunk staged (vmcnt0) + all readers of b done
    }

    // ---- cross-lane top-2 merge within each 16-lane col group ----
#pragma unroll
    for (int rf = 0; rf < RF; ++rf)
#pragma unroll
        for (int r = 0; r < 4; ++r) {
            float v1 = m1[rf][r], v2 = m2[rf][r]; int ii = i1[rf][r];
#pragma unroll
            for (int mk = 1; mk < 16; mk <<= 1) {
                float o1 = __shfl_xor(v1, mk, 64);
                float o2 = __shfl_xor(v2, mk, 64);
                int   oi = __shfl_xor(ii, mk, 64);
                float n2 = fminf(fminf(v2, o2), fmaxf(v1, o1));  // global 2nd-min
                if (o1 < v1 || (o1 == v1 && oi < ii)) { v1 = o1; ii = oi; }
                v2 = n2;
            }
            if (l15 == 0) {
                int row = row0 + rf * 16 + l4 * 4 + r;
                fidx_out[row] = (float)ii;
                if (v2 - v1 <= FLAG_M) {           // near-tie: append for exact rescore
                    int pos = atomicAdd(count, 1); // list order nondet; per-row results
                    list[pos] = row;               // independent -> output deterministic
                }
            }
        }
}

// -------- pass B: exact rescore, RPG rows per block-group --------
// Per (row,code): sequential fp32 fmac dot (i ascending, x/y/z/w), dist =
// (sxx+scc) - 2*dot, tie -> lowest k. Bit-identical to the round-1 recipe.
__global__ __launch_bounds__(256) void exact_fix_kernel(
    const float* __restrict__ x, const float* __restrict__ cb,
    const float* __restrict__ scc, const int* __restrict__ list,
    const int* __restrict__ count, float* __restrict__ fidx_out)
{
    __shared__ float4 Xs[RPG][32];
    __shared__ float  sxxs[RPG];
    __shared__ float  wrv[RPG][4];
    __shared__ int    wri[RPG][4];
    __shared__ int    rows_s[RPG];

    const int tid  = threadIdx.x;
    const int lane = tid & 63;
    const int wv   = tid >> 6;
    const int nflag = count[0];
    const int ngroups = (nflag + RPG - 1) / RPG;

    for (int g = blockIdx.x; g < ngroups; g += gridDim.x) {
        const int nr = min(RPG, nflag - g * RPG);
        if (tid < RPG)
            rows_s[tid] = list[g * RPG + min(tid, nr - 1)];   // dup last for tail
        __syncthreads();
        {   // stage 8 rows x 32 float4
            int r = tid >> 5, i = tid & 31;
            Xs[r][i] = reinterpret_cast<const float4*>(x)[(long)rows_s[r] * 32 + i];
        }
        __syncthreads();
        if (tid < RPG) {   // per-row sxx, sequential order
            float s = 0.f;
            for (int i = 0; i < 32; ++i) {
                float4 v = Xs[tid][i];
                s += v.x * v.x; s += v.y * v.y; s += v.z * v.z; s += v.w * v.w;
            }
            sxxs[tid] = s;
        }
        __syncthreads();

        // 4 codes per thread: k = tid*4+j (in-thread ascending)
        float acc[RPG][4];
#pragma unroll
        for (int r = 0; r < RPG; ++r)
#pragma unroll
            for (int j = 0; j < 4; ++j) acc[r][j] = 0.f;

        const float4* crow = reinterpret_cast<const float4*>(cb) + (tid * 4) * 32;
        for (int i = 0; i < 32; ++i) {
            float4 xv[RPG];
#pragma unroll
            for (int r = 0; r < RPG; ++r) xv[r] = Xs[r][i];
#pragma unroll
            for (int j = 0; j < 4; ++j) {
                float4 c = crow[j * 32 + i];
#pragma unroll
                for (int r = 0; r < RPG; ++r) {
                    acc[r][j] += xv[r].x * c.x;
                    acc[r][j] += xv[r].y * c.y;
                    acc[r][j] += xv[r].z * c.z;
                    acc[r][j] += xv[r].w * c.w;
                }
            }
        }

#pragma unroll
        for (int r = 0; r < RPG; ++r) {
            float bv = 3.4e38f; int bi = 0;
            const float sxxv = sxxs[r];
#pragma unroll
            for (int j = 0; j < 4; ++j) {
                int k = tid * 4 + j;
                float s1 = sxxv + scc[k];          // np: (sxx + scc)
                float dist = s1 - 2.0f * acc[r][j]; // np: ... - 2*dot
                if (dist < bv) { bv = dist; bi = k; }
            }
            // wave reduce (tie -> lowest k)
#pragma unroll
            for (int mk = 1; mk < 64; mk <<= 1) {
                float ov = __shfl_xor(bv, mk, 64);
                int   oi = __shfl_xor(bi, mk, 64);
                if (ov < bv || (ov == bv && oi < bi)) { bv = ov; bi = oi; }
            }
            if (lane == 0) { wrv[r][wv] = bv; wri[r][wv] = bi; }
        }
        __syncthreads();
        if (tid < RPG && tid < nr) {
            float bv = wrv[tid][0]; int bi = wri[tid][0];
#pragma unroll
            for (int e = 1; e < 4; ++e) {
                float v = wrv[tid][e]; int oi = wri[tid][e];
                if (v < bv || (v == bv && oi < bi)) { bv = v; bi = oi; }
            }
            fidx_out[rows_s[tid]] = (float)bi;
        }
        __syncthreads();
    }
}

// -------- phase 2: gather + STE output + loss partials --------
__global__ __launch_bounds__(256) void quant_kernel(
    const float* __restrict__ x, const float* __restrict__ cb,
    const float* __restrict__ fidx, float* __restrict__ out,
    double* __restrict__ partial)
{
    const int N4 = NROWS * (TAG_DIM / 4);
    double s = 0.0;
    for (int i = blockIdx.x * blockDim.x + threadIdx.x; i < N4; i += gridDim.x * blockDim.x) {
        int n = i >> 5;
        int d4 = i & 31;
        int k = (int)fidx[n];
        float4 xv = reinterpret_cast<const float4*>(x)[i];
        float4 qv = reinterpret_cast<const float4*>(cb)[k * 32 + d4];
        float dx = qv.x - xv.x, dy = qv.y - xv.y, dz = qv.z - xv.z, dw = qv.w - xv.w;
        float4 o;
        o.x = xv.x + dx; o.y = xv.y + dy; o.z = xv.z + dz; o.w = xv.w + dw;
        reinterpret_cast<float4*>(out)[i] = o;
        s += (double)dx * dx; s += (double)dy * dy; s += (double)dz * dz; s += (double)dw * dw;
    }
    __shared__ double sd[256];
    sd[threadIdx.x] = s;
    __syncthreads();
    for (int off = 128; off > 0; off >>= 1) {
        if (threadIdx.x < (unsigned)off) sd[threadIdx.x] += sd[threadIdx.x + off];
        __syncthreads();
    }
    if (threadIdx.x == 0) partial[blockIdx.x] = sd[0];
}

__global__ __launch_bounds__(256) void loss_kernel(
    const double* __restrict__ partial, int n, float* __restrict__ out_loss)
{
    __shared__ double sd[256];
    double s = 0.0;
    for (int i = threadIdx.x; i < n; i += 256) s += partial[i];
    sd[threadIdx.x] = s;
    __syncthreads();
    for (int off = 128; off > 0; off >>= 1) {
        if (threadIdx.x < (unsigned)off) sd[threadIdx.x] += sd[threadIdx.x + off];
        __syncthreads();
    }
    if (threadIdx.x == 0) {
        double mean = sd[0] / (double)((long long)NROWS * TAG_DIM);
        out_loss[0] = (float)(mean + 0.25 * mean);
    }
}

extern "C" void kernel_launch(void* const* d_in, const int* in_sizes, int n_in,
                              void* d_out, int out_size, void* d_ws, size_t ws_size,
                              hipStream_t stream) {
    const float* x  = (const float*)d_in[0];   // [131072][128]
    const float* cb = (const float*)d_in[1];   // [1024][128]
    float* out      = (float*)d_out;
    float* out_loss = out + (long)NROWS * TAG_DIM;
    float* out_fidx = out_loss + 1;            // 131072 indices as f32

    // ws layout (~1.05 MB): scc | cbf | list | count | partial
    char* wsb = (char*)d_ws;
    float*          scc     = (float*)(wsb);                     // 4 KB
    unsigned short* cbf     = (unsigned short*)(wsb + 4096);     // 512 KB
    int*            list    = (int*)(wsb + 528384);              // 512 KB
    int*            count   = (int*)(wsb + 1052672);             // 64 B
    double*         partial = (double*)(wsb + 1052736);          // 16 KB

    prep_kernel       <<<64, 256, 0, stream>>>(cb, scc, cbf, count);
    argmin_mfma_kernel<<<NROWS / 256, 256, 0, stream>>>(x, cbf, scc, out_fidx, list, count);
    exact_fix_kernel  <<<512, 256, 0, stream>>>(x, cb, scc, list, count, out_fidx);
    quant_kernel      <<<2048, 256, 0, stream>>>(x, cb, out_fidx, out, partial);
    loss_kernel       <<<1, 256, 0, stream>>>(partial, 2048, out_loss);
}